// Round 3
// baseline (425.710 us; speedup 1.0000x reference)
//
#include <hip/hip_runtime.h>
#include <hip/hip_bf16.h>
#include <math.h>

#define E 768
#define NH 12
#define HD 64

// ---------------------------------------------------------------------------
// Stage 1: trilinear border sample.  sampled[b,p,c] = sum_8corners w * x[b,1+t,c]
// One block per (b,p), threads over channels (coalesced).
// ---------------------------------------------------------------------------
__global__ void sample_kernel(const float* __restrict__ x,
                              const float* __restrict__ base_coords,
                              const float* __restrict__ offsets,
                              const int* __restrict__ gsize,
                              float* __restrict__ sampled,
                              int B, int P, int fullN)
{
    int bp = blockIdx.x;
    int b = bp / P, p = bp % P;
    int G = *gsize;
    float gm1 = (float)(G - 1);

    float cx = base_coords[p * 3 + 0] + offsets[bp * 3 + 0];
    float cy = base_coords[p * 3 + 1] + offsets[bp * 3 + 1];
    float cz = base_coords[p * 3 + 2] + offsets[bp * 3 + 2];
    cx = fminf(fmaxf(cx, -1.f), 1.f);
    cy = fminf(fmaxf(cy, -1.f), 1.f);
    cz = fminf(fmaxf(cz, -1.f), 1.f);

    float ix = (cx + 1.f) * 0.5f * gm1;
    float iy = (cy + 1.f) * 0.5f * gm1;
    float iz = (cz + 1.f) * 0.5f * gm1;
    float fx = floorf(ix), fy = floorf(iy), fz = floorf(iz);
    float wx = ix - fx, wy = iy - fy, wz = iz - fz;

    int x0 = (int)fminf(fmaxf(fx,       0.f), gm1);
    int x1 = (int)fminf(fmaxf(fx + 1.f, 0.f), gm1);
    int y0 = (int)fminf(fmaxf(fy,       0.f), gm1);
    int y1 = (int)fminf(fmaxf(fy + 1.f, 0.f), gm1);
    int z0 = (int)fminf(fmaxf(fz,       0.f), gm1);
    int z1 = (int)fminf(fmaxf(fz + 1.f, 0.f), gm1);

    // token index = (z*G + y)*G + x ; +1 skips CLS token
    int t000 = (z0 * G + y0) * G + x0;
    int t001 = (z0 * G + y0) * G + x1;
    int t010 = (z0 * G + y1) * G + x0;
    int t011 = (z0 * G + y1) * G + x1;
    int t100 = (z1 * G + y0) * G + x0;
    int t101 = (z1 * G + y0) * G + x1;
    int t110 = (z1 * G + y1) * G + x0;
    int t111 = (z1 * G + y1) * G + x1;

    float w000 = (1.f - wz) * (1.f - wy) * (1.f - wx);
    float w001 = (1.f - wz) * (1.f - wy) * wx;
    float w010 = (1.f - wz) * wy * (1.f - wx);
    float w011 = (1.f - wz) * wy * wx;
    float w100 = wz * (1.f - wy) * (1.f - wx);
    float w101 = wz * (1.f - wy) * wx;
    float w110 = wz * wy * (1.f - wx);
    float w111 = wz * wy * wx;

    const float* xb = x + ((size_t)b * fullN + 1) * E;
    float* outp = sampled + (size_t)bp * E;
    for (int c = threadIdx.x; c < E; c += blockDim.x) {
        float v = w000 * xb[(size_t)t000 * E + c]
                + w001 * xb[(size_t)t001 * E + c]
                + w010 * xb[(size_t)t010 * E + c]
                + w011 * xb[(size_t)t011 * E + c]
                + w100 * xb[(size_t)t100 * E + c]
                + w101 * xb[(size_t)t101 * E + c]
                + w110 * xb[(size_t)t110 * E + c]
                + w111 * xb[(size_t)t111 * E + c];
        outp[c] = v;
    }
}

// ---------------------------------------------------------------------------
// fp32 NT GEMM: C[m][n] = sum_k A[m][k] * W[n][k] + bias[n]
// A: MxK row-major, W: NxK row-major (both contiguous along K -> coalesced).
// 64x64 tile per block, 256 threads, 4x4 per thread, TK=16.
// ---------------------------------------------------------------------------
__global__ __launch_bounds__(256) void gemm_nt(const float* __restrict__ A,
                                               const float* __restrict__ W,
                                               const float* __restrict__ bias,
                                               float* __restrict__ C,
                                               int M, int N, int K)
{
    __shared__ float As[16][68];  // [kk][m], +4 pad keeps float4 alignment
    __shared__ float Bs[16][68];  // [kk][n]

    int tx = threadIdx.x & 15;   // n sub-tile
    int ty = threadIdx.x >> 4;   // m sub-tile
    int m0 = blockIdx.y * 64;
    int n0 = blockIdx.x * 64;

    float acc[4][4] = {};

    for (int k0 = 0; k0 < K; k0 += 16) {
#pragma unroll
        for (int l = 0; l < 4; ++l) {
            int lin = threadIdx.x + l * 256;   // 0..1023
            int kk = lin & 15;
            int mm = lin >> 4;                 // 0..63
            As[kk][mm] = A[(size_t)(m0 + mm) * K + (k0 + kk)];
            Bs[kk][mm] = W[(size_t)(n0 + mm) * K + (k0 + kk)];
        }
        __syncthreads();
#pragma unroll
        for (int kk = 0; kk < 16; ++kk) {
            float4 av = *(const float4*)&As[kk][ty * 4];
            float4 bv = *(const float4*)&Bs[kk][tx * 4];
            float a[4] = {av.x, av.y, av.z, av.w};
            float bb[4] = {bv.x, bv.y, bv.z, bv.w};
#pragma unroll
            for (int i = 0; i < 4; ++i)
#pragma unroll
                for (int j = 0; j < 4; ++j)
                    acc[i][j] += a[i] * bb[j];
        }
        __syncthreads();
    }

    int n = n0 + tx * 4;
    float4 bvec = *(const float4*)&bias[n];
#pragma unroll
    for (int i = 0; i < 4; ++i) {
        int m = m0 + ty * 4 + i;
        float4 r;
        r.x = acc[i][0] + bvec.x;
        r.y = acc[i][1] + bvec.y;
        r.z = acc[i][2] + bvec.z;
        r.w = acc[i][3] + bvec.w;
        *(float4*)&C[(size_t)m * N + n] = r;
    }
}

// ---------------------------------------------------------------------------
// Stage 4: per-(b,h) attention over P points.
// kv rows: [k(768) | v(768)] per (b,p).
// One block of 64 threads per (b,h).
// ---------------------------------------------------------------------------
__global__ void attn_kernel(const float* __restrict__ q,
                            const float* __restrict__ kv,
                            float* __restrict__ ctx,
                            int B, int P)
{
    int bh = blockIdx.x;
    int b = bh / NH, h = bh % NH;
    int d = threadIdx.x;  // 0..63

    __shared__ float qs[HD];
    __shared__ float sc[64];  // P <= 64

    qs[d] = q[(size_t)b * E + h * HD + d];
    __syncthreads();

    if (d < P) {
        const float* kr = kv + ((size_t)(b * P + d)) * (2 * E) + h * HD;
        float s = 0.f;
#pragma unroll
        for (int e = 0; e < HD; ++e) s += qs[e] * kr[e];
        sc[d] = s * 0.125f;  // 1/sqrt(64)
    }
    __syncthreads();

    // softmax stats (computed redundantly by all threads)
    float mx = -INFINITY;
    for (int p = 0; p < P; ++p) mx = fmaxf(mx, sc[p]);
    float den = 0.f;
    for (int p = 0; p < P; ++p) den += __expf(sc[p] - mx);
    __syncthreads();
    if (d < P) sc[d] = __expf(sc[d] - mx) / den;
    __syncthreads();

    float acc = 0.f;
    for (int p = 0; p < P; ++p) {
        acc += sc[p] * kv[((size_t)(b * P + p)) * (2 * E) + E + h * HD + d];
    }
    ctx[(size_t)b * E + h * HD + d] = acc;
}

// ---------------------------------------------------------------------------
// Stage 6: out[b,n,c] = attn_out[b,c] * conf[b]  (101 MB write, HBM-bound)
// NOTE: overwrites ALL of d_out, including the scratch regions used by
// earlier stages (stream-ordered after their last read).
// ---------------------------------------------------------------------------
__global__ void bcast_kernel(const float* __restrict__ attn_out,
                             const float* __restrict__ conf,
                             float* __restrict__ out,
                             int fullN, int pc /* fullN*E/4 */)
{
    int b = blockIdx.y;
    float cf = conf[b];
    const float4* ao = (const float4*)(attn_out + (size_t)b * E);  // 192 vec4
    float4* ob = (float4*)(out + (size_t)b * fullN * E);
    int i = blockIdx.x * blockDim.x + threadIdx.x;
    if (i < pc) {
        int c4 = i % (E / 4);
        float4 v = ao[c4];
        v.x *= cf; v.y *= cf; v.z *= cf; v.w *= cf;
        ob[i] = v;
    }
}

// ---------------------------------------------------------------------------
extern "C" void kernel_launch(void* const* d_in, const int* in_sizes, int n_in,
                              void* d_out, int out_size, void* d_ws, size_t ws_size,
                              hipStream_t stream)
{
    const float* x      = (const float*)d_in[0];
    const float* bio    = (const float*)d_in[1];
    const float* bcrd   = (const float*)d_in[2];
    const float* offs   = (const float*)d_in[3];
    const float* conf   = (const float*)d_in[4];
    const float* spw    = (const float*)d_in[5];
    const float* spb    = (const float*)d_in[6];
    const float* ipw    = (const float*)d_in[7];
    const float* ipb    = (const float*)d_in[8];
    const float* opw    = (const float*)d_in[9];
    const float* opb    = (const float*)d_in[10];
    const int*   gsize  = (const int*)d_in[11];
    float* out = (float*)d_out;

    const int B     = in_sizes[1] / E;            // 64
    const int P     = in_sizes[2] / 3;            // 32
    const int fullN = in_sizes[0] / (B * E);      // 513
    const int M     = B * P;                      // 2048

    // Big intermediates live in d_out's front (100.8 MB total, we use 25.2 MB);
    // the final bcast_kernel overwrites all of d_out after their last use.
    // Small buffers (576 KB total) live in d_ws.
    float* sampled = out;                         // M*E      (6.3 MB)
    float* sproj   = sampled + (size_t)M * E;     // M*E      (6.3 MB)
    float* kv      = sproj + (size_t)M * E;       // M*2E     (12.6 MB)

    float* ws   = (float*)d_ws;
    float* q    = ws;                             // B*E
    float* ctx  = q + (size_t)B * E;              // B*E
    float* aout = ctx + (size_t)B * E;            // B*E

    // 1. trilinear sampling
    sample_kernel<<<M, 256, 0, stream>>>(x, bcrd, offs, gsize, sampled, B, P, fullN);

    // 2. sampled @ sample_proj_w^T + b   (M x 768, K=768)
    gemm_nt<<<dim3(E / 64, M / 64), 256, 0, stream>>>(sampled, spw, spb, sproj, M, E, E);

    // 3. k,v fused: sproj @ [Wk;Wv]^T + [bk;bv]  (M x 1536, K=768)
    gemm_nt<<<dim3(2 * E / 64, M / 64), 256, 0, stream>>>(sproj, ipw + (size_t)E * E,
                                                          ipb + E, kv, M, 2 * E, E);

    // 4. q = bio_embed @ Wq^T + bq  (B x 768)
    gemm_nt<<<dim3(E / 64, B / 64), 256, 0, stream>>>(bio, ipw, ipb, q, B, E, E);

    // 5. attention
    attn_kernel<<<B * NH, 64, 0, stream>>>(q, kv, ctx, B, P);

    // 6. attn_out = ctx @ out_proj_w^T + b  (B x 768)
    gemm_nt<<<dim3(E / 64, B / 64), 256, 0, stream>>>(ctx, opw, opb, aout, B, E, E);

    // 7. broadcast * confidence (overwrites every element of d_out)
    int pc = fullN * E / 4;
    bcast_kernel<<<dim3((pc + 255) / 256, B), 256, 0, stream>>>(aout, conf, out, fullN, pc);
}

// Round 4
// 313.564 us; speedup vs baseline: 1.3577x; 1.3577x over previous
//
#include <hip/hip_runtime.h>
#include <hip/hip_bf16.h>
#include <math.h>

#define E 768
#define NH 12
#define HD 64

typedef __attribute__((ext_vector_type(8))) short bf16x8;
typedef __attribute__((ext_vector_type(4))) float f32x4;

__device__ __forceinline__ unsigned short f2bf_rne(float f) {
    unsigned int u = __float_as_uint(f);
    u += 0x7FFF + ((u >> 16) & 1);   // round-to-nearest-even
    return (unsigned short)(u >> 16);
}

// ---------------------------------------------------------------------------
// fp32 -> bf16 weight conversion
// ---------------------------------------------------------------------------
__global__ void conv_bf16(const float* __restrict__ src,
                          unsigned short* __restrict__ dst, int n)
{
    int i = blockIdx.x * blockDim.x + threadIdx.x;
    if (i < n) dst[i] = f2bf_rne(src[i]);
}

// ---------------------------------------------------------------------------
// Stage 1: trilinear border sample -> bf16 output (MFMA A-operand).
// One block per (b,p), threads over channels (coalesced).
// ---------------------------------------------------------------------------
__global__ void sample_kernel(const float* __restrict__ x,
                              const float* __restrict__ base_coords,
                              const float* __restrict__ offsets,
                              const int* __restrict__ gsize,
                              unsigned short* __restrict__ sampled,
                              int B, int P, int fullN)
{
    int bp = blockIdx.x;
    int b = bp / P, p = bp % P;
    int G = *gsize;
    float gm1 = (float)(G - 1);

    float cx = base_coords[p * 3 + 0] + offsets[bp * 3 + 0];
    float cy = base_coords[p * 3 + 1] + offsets[bp * 3 + 1];
    float cz = base_coords[p * 3 + 2] + offsets[bp * 3 + 2];
    cx = fminf(fmaxf(cx, -1.f), 1.f);
    cy = fminf(fmaxf(cy, -1.f), 1.f);
    cz = fminf(fmaxf(cz, -1.f), 1.f);

    float ix = (cx + 1.f) * 0.5f * gm1;
    float iy = (cy + 1.f) * 0.5f * gm1;
    float iz = (cz + 1.f) * 0.5f * gm1;
    float fx = floorf(ix), fy = floorf(iy), fz = floorf(iz);
    float wx = ix - fx, wy = iy - fy, wz = iz - fz;

    int x0 = (int)fminf(fmaxf(fx,       0.f), gm1);
    int x1 = (int)fminf(fmaxf(fx + 1.f, 0.f), gm1);
    int y0 = (int)fminf(fmaxf(fy,       0.f), gm1);
    int y1 = (int)fminf(fmaxf(fy + 1.f, 0.f), gm1);
    int z0 = (int)fminf(fmaxf(fz,       0.f), gm1);
    int z1 = (int)fminf(fmaxf(fz + 1.f, 0.f), gm1);

    int t000 = (z0 * G + y0) * G + x0;
    int t001 = (z0 * G + y0) * G + x1;
    int t010 = (z0 * G + y1) * G + x0;
    int t011 = (z0 * G + y1) * G + x1;
    int t100 = (z1 * G + y0) * G + x0;
    int t101 = (z1 * G + y0) * G + x1;
    int t110 = (z1 * G + y1) * G + x0;
    int t111 = (z1 * G + y1) * G + x1;

    float w000 = (1.f - wz) * (1.f - wy) * (1.f - wx);
    float w001 = (1.f - wz) * (1.f - wy) * wx;
    float w010 = (1.f - wz) * wy * (1.f - wx);
    float w011 = (1.f - wz) * wy * wx;
    float w100 = wz * (1.f - wy) * (1.f - wx);
    float w101 = wz * (1.f - wy) * wx;
    float w110 = wz * wy * (1.f - wx);
    float w111 = wz * wy * wx;

    const float* xb = x + ((size_t)b * fullN + 1) * E;
    unsigned short* outp = sampled + (size_t)bp * E;
    for (int c = threadIdx.x; c < E; c += blockDim.x) {
        float v = w000 * xb[(size_t)t000 * E + c]
                + w001 * xb[(size_t)t001 * E + c]
                + w010 * xb[(size_t)t010 * E + c]
                + w011 * xb[(size_t)t011 * E + c]
                + w100 * xb[(size_t)t100 * E + c]
                + w101 * xb[(size_t)t101 * E + c]
                + w110 * xb[(size_t)t110 * E + c]
                + w111 * xb[(size_t)t111 * E + c];
        outp[c] = f2bf_rne(v);
    }
}

// ---------------------------------------------------------------------------
// bf16 MFMA NT GEMM (m97 structure): C[m][n] = sum_k A[m][k]*W[n][k] + bias[n]
// A: MxK bf16 row-major; W: NxK bf16 row-major. 128x128 tile, 256 thr = 4 waves
// (2x2), each wave 64x64 via 4x4 grid of 16x16x32 MFMAs. BK=32.
// Staging via global_load_lds width=16 (wave-uniform base + lane*16).
// ---------------------------------------------------------------------------
template <bool OUT_BF16>
__global__ __launch_bounds__(256) void gemm_bf16_nt(
    const unsigned short* __restrict__ A,
    const unsigned short* __restrict__ W,
    const float* __restrict__ bias,
    void* __restrict__ C,
    int M, int N, int K)
{
    __shared__ unsigned short lsA[128 * 32];
    __shared__ unsigned short lsB[128 * 32];

    int wv = threadIdx.x >> 6;        // wave 0..3
    int ln = threadIdx.x & 63;
    int m0 = blockIdx.y * 128;
    int n0 = blockIdx.x * 128;
    int wm = (wv & 1) * 64;           // wave row offset
    int wn = (wv >> 1) * 64;          // wave col offset

    f32x4 acc[4][4] = {};

    int srow = ln >> 2;               // 0..15 row within 16-row chunk
    int scol = (ln & 3) * 8;          // bf16 col within 32 (16B granules)

    for (int k0 = 0; k0 < K; k0 += 32) {
#pragma unroll
        for (int c = 0; c < 2; ++c) {
            int chunk = wv * 2 + c;                    // 0..7 (16 rows each)
            int row = chunk * 16 + srow;
            const unsigned short* ga = A + (size_t)(m0 + row) * K + k0 + scol;
            const unsigned short* gw = W + (size_t)(n0 + row) * K + k0 + scol;
            __builtin_amdgcn_global_load_lds(
                (const __attribute__((address_space(1))) unsigned int*)ga,
                (__attribute__((address_space(3))) unsigned int*)(lsA + chunk * 16 * 32),
                16, 0, 0);
            __builtin_amdgcn_global_load_lds(
                (const __attribute__((address_space(1))) unsigned int*)gw,
                (__attribute__((address_space(3))) unsigned int*)(lsB + chunk * 16 * 32),
                16, 0, 0);
        }
        __syncthreads();

        // fragments: A[m = ln&15][k = (ln>>4)*8 + j], same for B (NT layout)
        int kq = (ln >> 4) * 8;
        int rsel = ln & 15;
        bf16x8 af[4], bfr[4];
#pragma unroll
        for (int i = 0; i < 4; ++i) {
            af[i]  = *(const bf16x8*)&lsA[(wm + i * 16 + rsel) * 32 + kq];
            bfr[i] = *(const bf16x8*)&lsB[(wn + i * 16 + rsel) * 32 + kq];
        }
#pragma unroll
        for (int i = 0; i < 4; ++i)
#pragma unroll
            for (int j = 0; j < 4; ++j)
                acc[i][j] = __builtin_amdgcn_mfma_f32_16x16x32_bf16(
                    af[i], bfr[j], acc[i][j], 0, 0, 0);
        __syncthreads();
    }

    // epilogue: C/D layout col = ln&15, row = (ln>>4)*4 + r  [m89-verified]
    int cr = (ln >> 4) * 4;
    int cc = ln & 15;
#pragma unroll
    for (int j = 0; j < 4; ++j) {
        int col = n0 + wn + j * 16 + cc;
        float bv = bias[col];
#pragma unroll
        for (int i = 0; i < 4; ++i) {
#pragma unroll
            for (int r = 0; r < 4; ++r) {
                int row = m0 + wm + i * 16 + cr + r;
                float v = acc[i][j][r] + bv;
                if (OUT_BF16)
                    ((unsigned short*)C)[(size_t)row * N + col] = f2bf_rne(v);
                else
                    ((float*)C)[(size_t)row * N + col] = v;
            }
        }
    }
}

// ---------------------------------------------------------------------------
// Small-M fp32 GEMM (M=64): one wave per output element, shuffle-reduced dot.
// C[m][n] = dot(A[m,:], W[n,:]) + bias[n]
// ---------------------------------------------------------------------------
__global__ void matvec_nt(const float* __restrict__ A,
                          const float* __restrict__ W,
                          const float* __restrict__ bias,
                          float* __restrict__ C,
                          int M, int N, int K)
{
    int wid = blockIdx.x * (blockDim.x >> 6) + (threadIdx.x >> 6);
    int ln = threadIdx.x & 63;
    if (wid >= M * N) return;
    int m = wid / N, n = wid % N;
    const float* a = A + (size_t)m * K;
    const float* w = W + (size_t)n * K;
    float s = 0.f;
    for (int k = ln; k < K; k += 64) s += a[k] * w[k];
#pragma unroll
    for (int off = 32; off; off >>= 1) s += __shfl_down(s, off);
    if (ln == 0) C[wid] = s + bias[n];
}

// ---------------------------------------------------------------------------
// Stage 4: per-(b,h) attention over P points. kv rows: [k(768) | v(768)].
// ---------------------------------------------------------------------------
__global__ void attn_kernel(const float* __restrict__ q,
                            const float* __restrict__ kv,
                            float* __restrict__ ctx,
                            int B, int P)
{
    int bh = blockIdx.x;
    int b = bh / NH, h = bh % NH;
    int d = threadIdx.x;  // 0..63

    __shared__ float qs[HD];
    __shared__ float sc[64];

    qs[d] = q[(size_t)b * E + h * HD + d];
    __syncthreads();

    if (d < P) {
        const float* kr = kv + ((size_t)(b * P + d)) * (2 * E) + h * HD;
        float s = 0.f;
#pragma unroll
        for (int e = 0; e < HD; ++e) s += qs[e] * kr[e];
        sc[d] = s * 0.125f;
    }
    __syncthreads();

    float mx = -INFINITY;
    for (int p = 0; p < P; ++p) mx = fmaxf(mx, sc[p]);
    float den = 0.f;
    for (int p = 0; p < P; ++p) den += __expf(sc[p] - mx);
    __syncthreads();
    if (d < P) sc[d] = __expf(sc[d] - mx) / den;
    __syncthreads();

    float acc = 0.f;
    for (int p = 0; p < P; ++p)
        acc += sc[p] * kv[((size_t)(b * P + p)) * (2 * E) + E + h * HD + d];
    ctx[(size_t)b * E + h * HD + d] = acc;
}

// ---------------------------------------------------------------------------
// Stage 6: out[b,n,c] = attn_out[b,c] * conf[b].  Overwrites all of d_out
// (attn_out lives in d_ws, so no read/write race).
// ---------------------------------------------------------------------------
__global__ void bcast_kernel(const float* __restrict__ attn_out,
                             const float* __restrict__ conf,
                             float* __restrict__ out,
                             int fullN, int pc)
{
    int b = blockIdx.y;
    float cf = conf[b];
    const float4* ao = (const float4*)(attn_out + (size_t)b * E);
    float4* ob = (float4*)(out + (size_t)b * fullN * E);
    int i = blockIdx.x * blockDim.x + threadIdx.x;
    if (i < pc) {
        int c4 = i % (E / 4);
        float4 v = ao[c4];
        v.x *= cf; v.y *= cf; v.z *= cf; v.w *= cf;
        ob[i] = v;
    }
}

// ---------------------------------------------------------------------------
extern "C" void kernel_launch(void* const* d_in, const int* in_sizes, int n_in,
                              void* d_out, int out_size, void* d_ws, size_t ws_size,
                              hipStream_t stream)
{
    const float* x      = (const float*)d_in[0];
    const float* bio    = (const float*)d_in[1];
    const float* bcrd   = (const float*)d_in[2];
    const float* offs   = (const float*)d_in[3];
    const float* conf   = (const float*)d_in[4];
    const float* spw    = (const float*)d_in[5];
    const float* spb    = (const float*)d_in[6];
    const float* ipw    = (const float*)d_in[7];
    const float* ipb    = (const float*)d_in[8];
    const float* opw    = (const float*)d_in[9];
    const float* opb    = (const float*)d_in[10];
    const int*   gsize  = (const int*)d_in[11];
    float* out = (float*)d_out;

    const int B     = in_sizes[1] / E;            // 64
    const int P     = in_sizes[2] / 3;            // 32
    const int fullN = in_sizes[0] / (B * E);      // 513
    const int M     = B * P;                      // 2048

    // All big intermediates live in d_out's front (~22.8 MB of 100.8 MB);
    // bcast_kernel overwrites all of d_out last. aout lives in d_ws (proven
    // safe footprint from R3: <=576 KB).
    char* base = (char*)d_out;
    unsigned short* sampled_bf = (unsigned short*)(base + 0);          // 3.0 MB
    unsigned short* sproj_bf   = (unsigned short*)(base + 3145728);    // 3.0 MB
    unsigned short* spw_bf     = (unsigned short*)(base + 6291456);    // 1.125 MB
    unsigned short* ipwkv_bf   = (unsigned short*)(base + 7471104);    // 2.25 MB
    float*          kv         = (float*)(base + 9830400);             // 12.6 MB
    float*          q          = (float*)(base + 22413312);            // 192 KB
    float*          ctx        = (float*)(base + 22609920);            // 192 KB
    float*          aout       = (float*)d_ws;                         // 192 KB

    // 0. weight conversion fp32 -> bf16
    int n_spw = E * E;                // 589824
    int n_kvw = 2 * E * E;            // 1179648
    conv_bf16<<<(n_spw + 255) / 256, 256, 0, stream>>>(spw, spw_bf, n_spw);
    conv_bf16<<<(n_kvw + 255) / 256, 256, 0, stream>>>(ipw + (size_t)E * E, ipwkv_bf, n_kvw);

    // 1. trilinear sampling -> bf16
    sample_kernel<<<M, 256, 0, stream>>>(x, bcrd, offs, gsize, sampled_bf, B, P, fullN);

    // 2. sproj = sampled @ spw^T + spb  (2048 x 768, K=768) -> bf16
    gemm_bf16_nt<true><<<dim3(E / 128, M / 128), 256, 0, stream>>>(
        sampled_bf, spw_bf, spb, sproj_bf, M, E, E);

    // 3. kv = sproj @ [Wk;Wv]^T + [bk;bv]  (2048 x 1536, K=768) -> fp32
    gemm_bf16_nt<false><<<dim3(2 * E / 128, M / 128), 256, 0, stream>>>(
        sproj_bf, ipwkv_bf, ipb + E, kv, M, 2 * E, E);

    // 4. q = bio @ Wq^T + bq  (64 x 768, fp32, wave-per-output)
    {
        int tot = B * E;  // 49152 waves
        matvec_nt<<<(tot + 3) / 4, 256, 0, stream>>>(bio, ipw, ipb, q, B, E, E);
    }

    // 5. attention
    attn_kernel<<<B * NH, 64, 0, stream>>>(q, kv, ctx, B, P);

    // 6. aout = ctx @ out_proj_w^T + opb  (64 x 768, fp32)
    {
        int tot = B * E;
        matvec_nt<<<(tot + 3) / 4, 256, 0, stream>>>(ctx, opw, opb, aout, B, E, E);
    }

    // 7. broadcast * confidence (overwrites every element of d_out)
    int pc = fullN * E / 4;
    bcast_kernel<<<dim3((pc + 255) / 256, B), 256, 0, stream>>>(aout, conf, out, fullN, pc);
}